// Round 1
// 238.917 us; speedup vs baseline: 1.0079x; 1.0079x over previous
//
#include <hip/hip_runtime.h>
#include <hip/hip_bf16.h>

// Problem: B=8, S=4096, D=768
//   y = tanh(x @ W); scores = y . v; w = softmax_S(scores); out = sum_s w * x
constexpr int Bb = 8;
constexpr int Ss = 4096;
constexpr int Dd = 768;
constexpr int Mm = Bb * Ss;      // 32768 rows

typedef __bf16 bf16x8 __attribute__((ext_vector_type(8)));
typedef __bf16 bf16x4 __attribute__((ext_vector_type(4)));
typedef float f32x4 __attribute__((ext_vector_type(4)));

__device__ __forceinline__ float fast_tanh(float x) {
    return 1.f - 2.f / (__expf(2.f * x) + 1.f);
}

__device__ __forceinline__ void load_lds16(const void* g, void* l) {
    __builtin_amdgcn_global_load_lds(
        (const __attribute__((address_space(1))) unsigned int*)g,
        (__attribute__((address_space(3))) unsigned int*)l, 16, 0, 0);
}

// ---------------- Kernel 0: W[k][n] fp32 -> Wt[n][k] bf16, with the LDS
// bank-swizzle PRE-BAKED into the global layout: within each 64B k-chunk of
// row n, 16B slot s holds original slot s ^ ((n>>1)&3). global_load_lds then
// writes LDS linearly and the GEMM reads with the same XOR -> 2-way max
// bank aliasing (free) instead of 8-way.
__global__ __launch_bounds__(256) void convW(const float* __restrict__ W,
                                             __bf16* __restrict__ Wt) {
    __shared__ float tile[32][33];
    const int tx = threadIdx.x & 31;
    const int ty = threadIdx.x >> 5;
    const int kb = blockIdx.x * 32;
    const int nb = blockIdx.y * 32;
#pragma unroll
    for (int i = 0; i < 32; i += 8)
        tile[ty + i][tx] = W[(size_t)(kb + ty + i) * Dd + nb + tx];
    __syncthreads();
#pragma unroll
    for (int i = 0; i < 32; i += 8) {
        const int n = nb + ty + i;
        const int txs = (tx & 7) | ((((tx >> 3) & 3) ^ ((n >> 1) & 3)) << 3);
        Wt[(size_t)n * Dd + kb + txs] = (__bf16)tile[tx][ty + i];
    }
}

// ---------------- Kernel 1: scores[m] += sum_n v[n]*tanh( (x@W)[m][n] )
// BM=128 x BN=256 tile, n-split 3 (score partials additive across n-blocks).
// 512 threads = 8 waves (2 wm x 4 wn); per wave 4 m-frags x 4 n-frags:
// 16 MFMA per 8 ds_read_b128 (ratio 2.0 vs old 1.5), acc = 64 regs.
// K streamed in 24 steps of 32. A: register-staged fp32->bf16 with XOR-
// swizzled ds_write_b128. B: global_load_lds width=16 from pre-swizzled
// L2-resident Wt. Double-buffered LDS (48 KB), ONE barrier per kstep;
// prefetch issued right after the barrier (T14 split: load early, cvt+write
// after MFMAs). Readers XOR the 16B slot with (row>>1)&3 -> conflict-free.
__global__ __launch_bounds__(512, 4) void scores_gemm(
    const float* __restrict__ x, const __bf16* __restrict__ Wt,
    const float* __restrict__ v, float* __restrict__ scores) {
    __shared__ __bf16 As[2][128 * 32];    // 2 x 8 KB
    __shared__ __bf16 Bs[2][256 * 32];    // 2 x 16 KB
    __shared__ float ssc[8][64];

    const int t = threadIdx.x;
    const int nb = blockIdx.x;            // 0..2
    const int mb = blockIdx.y;            // 0..255
    const int lane = t & 63;
    const int wave = t >> 6;
    const int wm = wave >> 2;             // 0..1 (64-row half)
    const int wn = wave & 3;              // 0..3 (64-col slice)
    const int quad = lane >> 4;
    const int lid = lane & 15;
    // read-side swizzle: frag rows are base(mult of 16)+lid -> key=(lid>>1)&3
    const int rslot = ((quad ^ ((lid >> 1) & 3)) * 8);

    // A staging: thread t -> row t>>2 (0..127), raw 16B slot t&3 (8 floats)
    const int arow = t >> 2;
    const int aslotraw = t & 3;
    const int aslot = aslotraw ^ ((arow >> 1) & 3);
    const float* agp = x + (size_t)(mb * 128 + arow) * Dd + aslotraw * 8;
    const int awr = arow * 32 + aslot * 8;    // bf16 index into As[buf]

    // B staging: 2 x 16B per thread, flat j*8192 + t*16 bytes over [256 x 64B]
    const __bf16* bg[2];
    int bl[2];
#pragma unroll
    for (int j = 0; j < 2; ++j) {
        const int flat = j * 8192 + t * 16;   // bytes
        const int col = flat >> 6;
        bg[j] = Wt + (size_t)(nb * 256 + col) * Dd + ((flat & 63) >> 1);
        bl[j] = flat >> 1;                    // bf16 index into Bs[buf]
    }

    f32x4 acc[4][4];
#pragma unroll
    for (int tm = 0; tm < 4; ++tm)
#pragma unroll
        for (int nt = 0; nt < 4; ++nt) acc[tm][nt] = (f32x4){0.f, 0.f, 0.f, 0.f};

    // ---- prologue: stage kstep 0 into buf 0
    {
        const float4 a0 = *(const float4*)(agp);
        const float4 a1 = *(const float4*)(agp + 4);
        bf16x8 pa;
        pa[0] = (__bf16)a0.x; pa[1] = (__bf16)a0.y; pa[2] = (__bf16)a0.z; pa[3] = (__bf16)a0.w;
        pa[4] = (__bf16)a1.x; pa[5] = (__bf16)a1.y; pa[6] = (__bf16)a1.z; pa[7] = (__bf16)a1.w;
        *(bf16x8*)(&As[0][awr]) = pa;
#pragma unroll
        for (int j = 0; j < 2; ++j) load_lds16(bg[j], &Bs[0][bl[j]]);
    }

    for (int kb = 0; kb < 24; ++kb) {
        const int p = kb & 1;
        __syncthreads();                  // buf p staged; buf 1-p free

        float4 a0n, a1n;
        if (kb < 23) {
            a0n = *(const float4*)(agp + (kb + 1) * 32);       // issued now
            a1n = *(const float4*)(agp + (kb + 1) * 32 + 4);   // used late
#pragma unroll
            for (int j = 0; j < 2; ++j)
                load_lds16(bg[j] + (kb + 1) * 32, &Bs[1 - p][bl[j]]);
        }

        bf16x8 af[4], bfr[4];
#pragma unroll
        for (int tm = 0; tm < 4; ++tm)
            af[tm] = *(const bf16x8*)(&As[p][(wm * 64 + tm * 16 + lid) * 32 + rslot]);
#pragma unroll
        for (int nt = 0; nt < 4; ++nt)
            bfr[nt] = *(const bf16x8*)(&Bs[p][(wn * 64 + nt * 16 + lid) * 32 + rslot]);

#pragma unroll
        for (int tm = 0; tm < 4; ++tm)
#pragma unroll
            for (int nt = 0; nt < 4; ++nt)
                acc[tm][nt] = __builtin_amdgcn_mfma_f32_16x16x32_bf16(af[tm], bfr[nt], acc[tm][nt], 0, 0, 0);

        if (kb < 23) {                    // convert + swizzled LDS write late
            bf16x8 pa;
            pa[0] = (__bf16)a0n.x; pa[1] = (__bf16)a0n.y; pa[2] = (__bf16)a0n.z; pa[3] = (__bf16)a0n.w;
            pa[4] = (__bf16)a1n.x; pa[5] = (__bf16)a1n.y; pa[6] = (__bf16)a1n.z; pa[7] = (__bf16)a1n.w;
            *(bf16x8*)(&As[1 - p][awr]) = pa;
        }
    }

    // ---- epilogue: fold tanh*v over this block's 256 cols, reduce to rows
    float vv[4];
#pragma unroll
    for (int nt = 0; nt < 4; ++nt)
        vv[nt] = v[nb * 256 + wn * 64 + nt * 16 + lid];

#pragma unroll
    for (int tm = 0; tm < 4; ++tm)
#pragma unroll
        for (int r = 0; r < 4; ++r) {
            float s = 0.f;
#pragma unroll
            for (int nt = 0; nt < 4; ++nt) s += vv[nt] * fast_tanh(acc[tm][nt][r]);
            // C layout: col=lid, row=quad*4+r
            s += __shfl_xor(s, 1);
            s += __shfl_xor(s, 2);
            s += __shfl_xor(s, 4);
            s += __shfl_xor(s, 8);
            if (lid == 0) ssc[wave][tm * 16 + quad * 4 + r] = s;
        }
    __syncthreads();
    if (t < 128) {
        const int wmh = t >> 6;           // which 64-row half
        const int rl = t & 63;
        float s = 0.f;
#pragma unroll
        for (int ww = 0; ww < 4; ++ww) s += ssc[wmh * 4 + ww][rl];
        atomicAdd(&scores[mb * 128 + t], s);
    }
}

// ---------------- Kernel 2: softmax over S per batch row -> normalized weights
__global__ __launch_bounds__(256) void softmax_k(const float* __restrict__ scores,
                                                 float* __restrict__ weights) {
    const int b = blockIdx.x;
    const int t = threadIdx.x;
    const float* s = scores + (size_t)b * Ss;
    float* wgt = weights + (size_t)b * Ss;
    __shared__ float red[256];

    float mx = -1e30f;
    for (int i = t; i < Ss; i += 256) mx = fmaxf(mx, s[i]);
    red[t] = mx;
    __syncthreads();
    for (int o = 128; o > 0; o >>= 1) {
        if (t < o) red[t] = fmaxf(red[t], red[t + o]);
        __syncthreads();
    }
    mx = red[0];
    __syncthreads();
    float sum = 0.f;
    for (int i = t; i < Ss; i += 256) {
        const float e = __expf(s[i] - mx);
        wgt[i] = e;
        sum += e;
    }
    red[t] = sum;
    __syncthreads();
    for (int o = 128; o > 0; o >>= 1) {
        if (t < o) red[t] += red[t + o];
        __syncthreads();
    }
    const float inv = 1.f / red[0];
    for (int i = t; i < Ss; i += 256) wgt[i] *= inv;
}

// ---------------- Kernel 3a: per-chunk partial pool (no atomics)
// grid = (128 chunks, B) = 1024 blocks x 192 thr (4 blocks/CU, 12 waves/CU)
__global__ __launch_bounds__(192) void pool1(const float* __restrict__ x,
                                             const float* __restrict__ weights,
                                             float* __restrict__ partial) {
    const int b = blockIdx.y;
    const int c = blockIdx.x;            // 128 chunks x 32 rows
    const int t = threadIdx.x;           // owns float4 at d = t*4
    const float* base = x + ((size_t)b * Ss + c * 32) * Dd;
    const float* wrow = weights + (size_t)b * Ss + c * 32;
    float4 acc = make_float4(0.f, 0.f, 0.f, 0.f);
#pragma unroll 8
    for (int i = 0; i < 32; ++i) {
        const float ww = wrow[i];
        const float4 xv = *(const float4*)(base + (size_t)i * Dd + t * 4);
        acc.x += ww * xv.x;
        acc.y += ww * xv.y;
        acc.z += ww * xv.z;
        acc.w += ww * xv.w;
    }
    *(float4*)(partial + ((size_t)(b * 128 + c)) * Dd + t * 4) = acc;
}

// ---------------- Kernel 3b: out[b][d] = sum_c partial[b][c][d]
__global__ __launch_bounds__(768) void pool2(const float* __restrict__ partial,
                                             float* __restrict__ out) {
    const int b = blockIdx.x;
    const int d = threadIdx.x;           // 0..767
    float s = 0.f;
#pragma unroll 8
    for (int c = 0; c < 128; ++c) s += partial[((size_t)(b * 128 + c)) * Dd + d];
    out[(size_t)b * Dd + d] = s;
}

extern "C" void kernel_launch(void* const* d_in, const int* in_sizes, int n_in,
                              void* d_out, int out_size, void* d_ws, size_t ws_size,
                              hipStream_t stream) {
    (void)in_sizes; (void)n_in; (void)ws_size; (void)out_size;
    const float* x = (const float*)d_in[0];
    const float* v = (const float*)d_in[1];
    const float* W = (const float*)d_in[2];

    char* ws = (char*)d_ws;
    __bf16* Wt = (__bf16*)ws;                             // 1,179,648 B
    float* scores = (float*)(ws + 1179648);               //   131,072 B
    float* weights = (float*)(ws + 1179648 + 131072);     //   131,072 B
    float* partial = (float*)(ws + 1179648 + 262144);     // 3,145,728 B (8*128*768 f32)

    hipMemsetAsync(scores, 0, Mm * sizeof(float), stream);

    convW<<<dim3(Dd / 32, Dd / 32), 256, 0, stream>>>(W, Wt);
    scores_gemm<<<dim3(3, Mm / 128), 512, 0, stream>>>(x, Wt, v, scores);
    softmax_k<<<dim3(Bb), 256, 0, stream>>>(scores, weights);
    pool1<<<dim3(128, Bb), 192, 0, stream>>>(x, weights, partial);
    pool2<<<dim3(Bb), 768, 0, stream>>>(partial, (float*)d_out);
}